// Round 8
// baseline (42.585 us; speedup 1.0000x reference)
//
#include <hip/hip_runtime.h>

#define BB 16
#define NN 2048
#define NFF 512
#define DD 4

#define ROWS 64        // K-rows per gemv block (4 waves x 16 rows)
#define WR 16          // rows per wave
#define YINT 32        // 32*64 = 2048 Wint rows
#define YTOT 40        // + 8*64 = 512 Wff rows
#define JC   256       // columns per x-block (64 lanes x 4 cols, float4)
#define NX   (NN / JC) // 8 column groups

// ---------------- Kernel 1: elementwise pre-pass ----------------
// X = sigmoid((V-1-th)*5) -> out_X ; T[b,i] = sum_d Xd*(1+0.95*stp-0.3*Xd) -> ws
// Zeroes cur (atomic accumulator) and the 8 tail counters.
// Per-block partial sums for the 4 per-batch scalars:
//   blocks [0,128):   p0 = sum T*xpre_int, p1 = sum T*Xd0   (8 blocks/batch)
//   blocks [128,160): p0 = sum FF*xpre_ff, p1 = sum FF*FF   (2 blocks/batch)
__global__ __launch_bounds__(256) void snn_pre(
    const float* __restrict__ FF, const float* __restrict__ V,
    const float* __restrict__ th, const float* __restrict__ Xbuf,
    const float* __restrict__ stp, const float* __restrict__ xpre_int,
    const float* __restrict__ xpre_ff,
    float* __restrict__ out_X, float* __restrict__ T,
    float* __restrict__ cur, float* __restrict__ scal_part,
    unsigned int* __restrict__ cnt)
{
    __shared__ float red[8];
    int idx = blockIdx.x * 256 + threadIdx.x;
    if (blockIdx.x == 0 && threadIdx.x < NX) cnt[threadIdx.x] = 0u;
    float p0, p1;
    if (idx < BB * NN) {
        float v = V[idx], t = th[idx];
        float x = 1.f / (1.f + expf(-(v - 1.f - t) * 5.f));
        out_X[idx] = x;
        cur[idx] = 0.f;
        float xd0 = Xbuf[idx];
        float acc = 0.f;
        #pragma unroll
        for (int d = 0; d < DD; ++d) {
            float xd = Xbuf[d * BB * NN + idx];
            float s  = stp[d * BB * NN + idx];
            acc += xd * (1.f + 0.95f * s - 0.3f * xd);
        }
        T[idx] = acc;
        p0 = acc * xpre_int[idx];
        p1 = acc * xd0;
    } else {
        int k = idx - BB * NN;
        float f = FF[k];
        p0 = f * xpre_ff[k];
        p1 = f * f;
    }
    #pragma unroll
    for (int o = 32; o; o >>= 1) { p0 += __shfl_xor(p0, o); p1 += __shfl_xor(p1, o); }
    int w = threadIdx.x >> 6;
    if ((threadIdx.x & 63) == 0) { red[w * 2] = p0; red[w * 2 + 1] = p1; }
    __syncthreads();
    if (threadIdx.x == 0) {
        scal_part[blockIdx.x * 2]     = red[0] + red[2] + red[4] + red[6];
        scal_part[blockIdx.x * 2 + 1] = red[1] + red[3] + red[5] + red[7];
    }
}

// ---------------- Kernel 2: split-K GEMV + atomic accumulate + tail ----------------
// Each block: 64 K-rows x 256 cols; wave0 atomicAdds the block's partials into
// cur (atomics are device-coherent on gfx950 -> no fences, no wbl2).
// __syncthreads() drains vmcnt(0), so data-atomics are globally performed
// before the counter atomic issues. The 40th arriver per column group reads
// totals back with atomicAdd(p,0.0f) (coherent read) and finalizes out_V.
__global__ __launch_bounds__(256) void snn_gemv(
    const float* __restrict__ Wint, const float* __restrict__ Wff,
    const float* __restrict__ T, const float* __restrict__ FF,
    const float* __restrict__ V, const float* __restrict__ xpost,
    const float* __restrict__ scal_part, const float* __restrict__ out_X,
    float* __restrict__ out_V, float* __restrict__ cur,
    unsigned int* __restrict__ cnt)
{
    __shared__ float  c_lds[ROWS * BB];          // 4 KB  [row][b]
    __shared__ float4 red[2 * BB * 64];          // 32 KB [buf][b][lane]
    __shared__ unsigned int tail_flag;
    __shared__ float csum[4 * BB];
    int y = blockIdx.y;
    const float* Wm; const float* OP; int i0, opstride;
    if (y < YINT) { Wm = Wint; OP = T;  i0 = y * ROWS;          opstride = NN;  }
    else          { Wm = Wff;  OP = FF; i0 = (y - YINT) * ROWS; opstride = NFF; }

    int t = threadIdx.x;
    #pragma unroll
    for (int k = 0; k < ROWS * BB / 256; ++k) {
        int e = k * 256 + t;
        int row = e >> 4, b = e & 15;
        c_lds[e] = OP[b * opstride + i0 + row];
    }
    __syncthreads();

    int w = t >> 6, l = t & 63;
    int j0 = blockIdx.x * JC + l * 4;

    // issue ALL 16 row loads up front (16 x 16B outstanding per lane)
    const float* wp = Wm + (size_t)(i0 + w * WR) * NN + j0;
    float4 buf[WR];
    #pragma unroll
    for (int r = 0; r < WR; ++r) buf[r] = *(const float4*)(wp + (size_t)r * NN);

    float4 acc[BB];
    #pragma unroll
    for (int b = 0; b < BB; ++b) acc[b] = make_float4(0.f, 0.f, 0.f, 0.f);

    #pragma unroll
    for (int r = 0; r < WR; ++r) {
        const float4* cb = (const float4*)&c_lds[(w * WR + r) * BB];
        float4 c0 = cb[0], c1 = cb[1], c2 = cb[2], c3 = cb[3];
        float4 wv = buf[r];
#define FMA4(b, cc) acc[b].x += (cc) * wv.x; acc[b].y += (cc) * wv.y; \
                    acc[b].z += (cc) * wv.z; acc[b].w += (cc) * wv.w;
        FMA4(0,  c0.x) FMA4(1,  c0.y) FMA4(2,  c0.z) FMA4(3,  c0.w)
        FMA4(4,  c1.x) FMA4(5,  c1.y) FMA4(6,  c1.z) FMA4(7,  c1.w)
        FMA4(8,  c2.x) FMA4(9,  c2.y) FMA4(10, c2.z) FMA4(11, c2.w)
        FMA4(12, c3.x) FMA4(13, c3.y) FMA4(14, c3.z) FMA4(15, c3.w)
#undef FMA4
    }

    // tree-reduce 4 waves: [b][lane] float4, contiguous b128 ops
    if (w >= 2) {
        float4* rb = &red[(w - 2) * BB * 64];
        #pragma unroll
        for (int b = 0; b < BB; ++b) rb[b * 64 + l] = acc[b];
    }
    __syncthreads();
    if (w < 2) {
        const float4* rb = &red[w * BB * 64];
        #pragma unroll
        for (int b = 0; b < BB; ++b) {
            float4 v = rb[b * 64 + l];
            acc[b].x += v.x; acc[b].y += v.y; acc[b].z += v.z; acc[b].w += v.w;
        }
    }
    __syncthreads();
    if (w == 1) {
        #pragma unroll
        for (int b = 0; b < BB; ++b) red[b * 64 + l] = acc[b];
    }
    __syncthreads();
    if (w == 0) {
        float* pp = cur + j0;
        #pragma unroll
        for (int b = 0; b < BB; ++b) {
            float4 v = red[b * 64 + l];
            atomicAdd(pp + (size_t)b * NN + 0, acc[b].x + v.x);
            atomicAdd(pp + (size_t)b * NN + 1, acc[b].y + v.y);
            atomicAdd(pp + (size_t)b * NN + 2, acc[b].z + v.z);
            atomicAdd(pp + (size_t)b * NN + 3, acc[b].w + v.w);
        }
    }

    // ---- last-block-per-column-group tail (atomics only, no fences) ----
    __syncthreads();                 // drains wave0's atomics (vmcnt(0))
    if (t == 0) {
        unsigned int old = atomicAdd(&cnt[blockIdx.x], 1u);
        tail_flag = (old == YTOT - 1) ? 1u : 0u;
    }
    __syncthreads();
    if (!tail_flag) return;

    // scalar sums: 64 threads compute csum[c][b], c in {c1,c2,c3,c4}
    if (t < 64) {
        int c = t >> 4, b = t & 15;
        float s = 0.f;
        if (c < 2) {
            #pragma unroll
            for (int k = 0; k < 8; ++k) s += scal_part[(b * 8 + k) * 2 + c];
        } else {
            #pragma unroll
            for (int k = 0; k < 2; ++k) s += scal_part[(128 + b * 2 + k) * 2 + (c - 2)];
        }
        csum[c * BB + b] = s;
    }
    __syncthreads();

    // finalize JC cols x 16 batches: thread t owns one column
    int j = blockIdx.x * JC + t;
    #pragma unroll
    for (int b = 0; b < BB; ++b) {
        int idx = b * NN + j;
        float s = atomicAdd(&cur[idx], 0.0f);   // coherent read of the total
        float x = out_X[idx];
        float c = s + 0.01f  * (csum[0 * BB + b] + csum[2 * BB + b]) * x
                    - 0.012f * (csum[1 * BB + b] + csum[3 * BB + b]) * xpost[idx];
        out_V[idx] = 0.9f * V[idx] * (1.f - x) + c;
    }
}

extern "C" void kernel_launch(void* const* d_in, const int* in_sizes, int n_in,
                              void* d_out, int out_size, void* d_ws, size_t ws_size,
                              hipStream_t stream) {
    const float* FF       = (const float*)d_in[0];
    const float* V        = (const float*)d_in[1];
    const float* th       = (const float*)d_in[2];
    const float* Xbuf     = (const float*)d_in[3];
    const float* stp      = (const float*)d_in[4];
    const float* xpre_int = (const float*)d_in[5];
    const float* xpost    = (const float*)d_in[6];
    const float* xpre_ff  = (const float*)d_in[7];
    const float* Wint     = (const float*)d_in[8];
    const float* Wff      = (const float*)d_in[9];
    float* out = (float*)d_out;
    float* ws  = (float*)d_ws;

    float* T    = ws;                               // 32768 floats
    float* cur  = ws + BB * NN;                     // 32768 floats (atomic accumulator)
    float* sp   = ws + 2 * BB * NN;                 // 320 floats
    unsigned int* cnt = (unsigned int*)(sp + 320);  // 8 uints

    snn_pre<<<(BB * NN + BB * NFF) / 256, 256, 0, stream>>>(
        FF, V, th, Xbuf, stp, xpre_int, xpre_ff, out, T, cur, sp, cnt);

    snn_gemv<<<dim3(NX, YTOT), 256, 0, stream>>>(
        Wint, Wff, T, FF, V, xpost, sp, out, out + BB * NN, cur, cnt);
}

// Round 9
// 19.420 us; speedup vs baseline: 2.1928x; 2.1928x over previous
//
#include <hip/hip_runtime.h>

#define BB 16
#define NN 2048
#define NFF 512
#define DD 4
#define BN (BB * NN)   // 32768

#define ROWS 64        // K-rows per gemv block (4 waves x 16 rows)
#define WR 16          // rows per wave
#define YINT 32        // 32*64 = 2048 Wint rows
#define YTOT 40        // + 8*64 = 512 Wff rows
#define JC   256       // columns per x-block (64 lanes x 4 cols, float4)
#define NX   (NN / JC) // 8 column groups

// ---------------- Kernel A: GEMV with in-block T compute + scal partials ----------------
// part[y][b][j] = sum_{i in y's 64 rows} OP[b,i] * W[i,j]
//   y in [0,32): W=Wint, OP=T computed in-block from Xbuf/stp
//   y in [32,40): W=Wff, OP=FF
// x==0 blocks also write scal_part[y][2][16]:
//   y<32:  (sum_row T*xpre_int, sum_row T*Xd0)
//   y>=32: (sum_row FF*xpre_ff, sum_row FF*FF)
__global__ __launch_bounds__(256) void snn_gemv(
    const float* __restrict__ Wint, const float* __restrict__ Wff,
    const float* __restrict__ Xbuf, const float* __restrict__ stp,
    const float* __restrict__ FF,
    const float* __restrict__ xpre_int, const float* __restrict__ xpre_ff,
    float* __restrict__ part, float* __restrict__ scal_part)
{
    __shared__ float  c_lds[ROWS * BB];          // 4 KB  [row][b]
    __shared__ float4 red[2 * BB * 64];          // 32 KB [buf][b][lane]
    int x = blockIdx.x, y = blockIdx.y;
    int t = threadIdx.x;
    const float* Wm; int i0;

    if (y < YINT) {
        i0 = y * ROWS; Wm = Wint;
        // T[row][b] = sum_d Xd*(1 + 0.95*stp - 0.3*Xd) over this 64-row slice
        #pragma unroll
        for (int k = 0; k < ROWS * BB / 256; ++k) {
            int e = k * 256 + t;
            int row = e >> 4, b = e & 15;
            int base = b * NN + i0 + row;
            float acc = 0.f;
            #pragma unroll
            for (int d = 0; d < DD; ++d) {
                float xd = Xbuf[d * BN + base];
                float s  = stp[d * BN + base];
                acc += xd * (1.f + 0.95f * s - 0.3f * xd);
            }
            c_lds[e] = acc;
        }
    } else {
        i0 = (y - YINT) * ROWS; Wm = Wff;
        #pragma unroll
        for (int k = 0; k < ROWS * BB / 256; ++k) {
            int e = k * 256 + t;
            int row = e >> 4, b = e & 15;
            c_lds[e] = FF[b * NFF + i0 + row];
        }
    }
    __syncthreads();

    // scal partials (x==0 blocks only; c_lds is read-only from here on)
    if (x == 0) {
        int b = t >> 4, rg = t & 15;     // 16 lanes-groups of 16 rows... rg covers 4 rows
        float s0 = 0.f, s1 = 0.f;
        if (y < YINT) {
            #pragma unroll
            for (int k = 0; k < 4; ++k) {
                int row = rg * 4 + k;
                float tv = c_lds[row * BB + b];
                s0 += tv * xpre_int[b * NN + i0 + row];
                s1 += tv * Xbuf[b * NN + i0 + row];          // Xd0
            }
        } else {
            #pragma unroll
            for (int k = 0; k < 4; ++k) {
                int row = rg * 4 + k;
                float f = c_lds[row * BB + b];
                s0 += f * xpre_ff[b * NFF + i0 + row];
                s1 += f * f;
            }
        }
        #pragma unroll
        for (int o = 1; o < 16; o <<= 1) { s0 += __shfl_xor(s0, o); s1 += __shfl_xor(s1, o); }
        if (rg == 0) {
            scal_part[y * 32 + b]      = s0;
            scal_part[y * 32 + 16 + b] = s1;
        }
    }

    int w = t >> 6, l = t & 63;
    int j0 = x * JC + l * 4;

    // issue ALL 16 row loads up front (16 x 16B outstanding per lane)
    const float* wp = Wm + (size_t)(i0 + w * WR) * NN + j0;
    float4 buf[WR];
    #pragma unroll
    for (int r = 0; r < WR; ++r) buf[r] = *(const float4*)(wp + (size_t)r * NN);

    float4 acc[BB];
    #pragma unroll
    for (int b = 0; b < BB; ++b) acc[b] = make_float4(0.f, 0.f, 0.f, 0.f);

    #pragma unroll
    for (int r = 0; r < WR; ++r) {
        const float4* cb = (const float4*)&c_lds[(w * WR + r) * BB];
        float4 c0 = cb[0], c1 = cb[1], c2 = cb[2], c3 = cb[3];
        float4 wv = buf[r];
#define FMA4(b, cc) acc[b].x += (cc) * wv.x; acc[b].y += (cc) * wv.y; \
                    acc[b].z += (cc) * wv.z; acc[b].w += (cc) * wv.w;
        FMA4(0,  c0.x) FMA4(1,  c0.y) FMA4(2,  c0.z) FMA4(3,  c0.w)
        FMA4(4,  c1.x) FMA4(5,  c1.y) FMA4(6,  c1.z) FMA4(7,  c1.w)
        FMA4(8,  c2.x) FMA4(9,  c2.y) FMA4(10, c2.z) FMA4(11, c2.w)
        FMA4(12, c3.x) FMA4(13, c3.y) FMA4(14, c3.z) FMA4(15, c3.w)
#undef FMA4
    }

    // tree-reduce 4 waves: [b][lane] float4, contiguous b128 ops
    if (w >= 2) {
        float4* rb = &red[(w - 2) * BB * 64];
        #pragma unroll
        for (int b = 0; b < BB; ++b) rb[b * 64 + l] = acc[b];
    }
    __syncthreads();
    if (w < 2) {
        const float4* rb = &red[w * BB * 64];
        #pragma unroll
        for (int b = 0; b < BB; ++b) {
            float4 v = rb[b * 64 + l];
            acc[b].x += v.x; acc[b].y += v.y; acc[b].z += v.z; acc[b].w += v.w;
        }
    }
    __syncthreads();
    if (w == 1) {
        #pragma unroll
        for (int b = 0; b < BB; ++b) red[b * 64 + l] = acc[b];
    }
    __syncthreads();
    if (w == 0) {
        float* pp = part + (size_t)y * BN + j0;
        #pragma unroll
        for (int b = 0; b < BB; ++b) {
            float4 v = red[b * 64 + l];
            acc[b].x += v.x; acc[b].y += v.y; acc[b].z += v.z; acc[b].w += v.w;
            *(float4*)(pp + (size_t)b * NN) = acc[b];
        }
    }
}

// ---------------- Kernel B: X + reduce partials + finalize ----------------
__global__ __launch_bounds__(256) void snn_post(
    const float* __restrict__ V, const float* __restrict__ th,
    const float* __restrict__ xpost,
    const float* __restrict__ part, const float* __restrict__ scal_part,
    float* __restrict__ out_X, float* __restrict__ out_V)
{
    int idx = blockIdx.x * 256 + threadIdx.x;
    int b = idx >> 11;                   // block-uniform
    float c1 = 0.f, c2 = 0.f, c3 = 0.f, c4 = 0.f;
    #pragma unroll
    for (int y = 0; y < YINT; ++y) {
        c1 += scal_part[y * 32 + b];
        c2 += scal_part[y * 32 + 16 + b];
    }
    #pragma unroll
    for (int y = YINT; y < YTOT; ++y) {
        c3 += scal_part[y * 32 + b];
        c4 += scal_part[y * 32 + 16 + b];
    }
    float v = V[idx];
    float x = 1.f / (1.f + expf(-(v - 1.f - th[idx]) * 5.f));
    out_X[idx] = x;
    float s = 0.f;
    #pragma unroll
    for (int y = 0; y < YTOT; ++y) s += part[(size_t)y * BN + idx];
    float c = s + 0.01f * (c1 + c3) * x - 0.012f * (c2 + c4) * xpost[idx];
    out_V[idx] = 0.9f * v * (1.f - x) + c;
}

extern "C" void kernel_launch(void* const* d_in, const int* in_sizes, int n_in,
                              void* d_out, int out_size, void* d_ws, size_t ws_size,
                              hipStream_t stream) {
    const float* FF       = (const float*)d_in[0];
    const float* V        = (const float*)d_in[1];
    const float* th       = (const float*)d_in[2];
    const float* Xbuf     = (const float*)d_in[3];
    const float* stp      = (const float*)d_in[4];
    const float* xpre_int = (const float*)d_in[5];
    const float* xpost    = (const float*)d_in[6];
    const float* xpre_ff  = (const float*)d_in[7];
    const float* Wint     = (const float*)d_in[8];
    const float* Wff      = (const float*)d_in[9];
    float* out = (float*)d_out;
    float* ws  = (float*)d_ws;

    float* part = ws;                    // 40 * 32768 floats (plain stores)
    float* sp   = ws + YTOT * BN;        // 1280 floats (plain stores)

    snn_gemv<<<dim3(NX, YTOT), 256, 0, stream>>>(
        Wint, Wff, Xbuf, stp, FF, xpre_int, xpre_ff, part, sp);

    snn_post<<<BN / 256, 256, 0, stream>>>(
        V, th, xpost, part, sp, out, out + BN);
}

// Round 10
// 18.769 us; speedup vs baseline: 2.2689x; 1.0347x over previous
//
#include <hip/hip_runtime.h>

#define BB 16
#define NN 2048
#define NFF 512
#define DD 4
#define BN (BB * NN)   // 32768

#define ROWS 64        // K-rows per gemv block (lane l <-> row l)
#define WR 16          // rows per wave in the compute loop
#define YINT 32        // 32*64 = 2048 Wint rows
#define YTOT 40        // + 8*64 = 512 Wff rows
#define JC   256       // columns per x-block (64 lanes x 4 cols, float4)
#define NX   (NN / JC) // 8 column groups

// ---------------- Kernel A: GEMV with coalesced in-block staging ----------------
// part[y][b][j] = sum_{i in y's 64 rows} OP[b,i] * W[i,j]
//   y in [0,32): W=Wint, OP=T computed in-block from Xbuf/stp
//   y in [32,40): W=Wff, OP=FF
// c_lds is b-major [16][64]: lane l covers row l -> every global read in
// staging is a coalesced 256B wave read; LDS writes are lane-consecutive.
// x==0 blocks also write scal_part[y][2][16] (coalesced, wave-parallel).
__global__ __launch_bounds__(256) void snn_gemv(
    const float* __restrict__ Wint, const float* __restrict__ Wff,
    const float* __restrict__ Xbuf, const float* __restrict__ stp,
    const float* __restrict__ FF,
    const float* __restrict__ xpre_int, const float* __restrict__ xpre_ff,
    float* __restrict__ part, float* __restrict__ scal_part)
{
    __shared__ __align__(16) float c_lds[BB * ROWS];   // 4 KB  [b][row]
    __shared__ float4 red[2 * BB * 64];                // 32 KB [buf][b][lane]
    int x = blockIdx.x, y = blockIdx.y;
    int t = threadIdx.x;
    int w = t >> 6, l = t & 63;
    const float* Wm; int i0;

    if (y < YINT) {
        i0 = y * ROWS; Wm = Wint;
        #pragma unroll
        for (int bb = 0; bb < 4; ++bb) {
            int b = w * 4 + bb;
            int base = b * NN + i0 + l;
            float acc = 0.f;
            #pragma unroll
            for (int d = 0; d < DD; ++d) {
                float xd = Xbuf[d * BN + base];   // coalesced 256B
                float s  = stp[d * BN + base];
                acc += xd * (1.f + 0.95f * s - 0.3f * xd);
            }
            c_lds[b * ROWS + l] = acc;            // lane-consecutive write
        }
    } else {
        i0 = (y - YINT) * ROWS; Wm = Wff;
        #pragma unroll
        for (int bb = 0; bb < 4; ++bb) {
            int b = w * 4 + bb;
            c_lds[b * ROWS + l] = FF[b * NFF + i0 + l];
        }
    }
    __syncthreads();

    // scal partials (x==0 blocks; all reads coalesced, wave-parallel)
    if (x == 0) {
        #pragma unroll
        for (int bb = 0; bb < 4; ++bb) {
            int b = w * 4 + bb;
            float tv = c_lds[b * ROWS + l];
            float s0, s1;
            if (y < YINT) {
                s0 = tv * xpre_int[b * NN + i0 + l];
                s1 = tv * Xbuf[b * NN + i0 + l];          // Xd0
            } else {
                s0 = tv * xpre_ff[b * NFF + i0 + l];
                s1 = tv * tv;
            }
            #pragma unroll
            for (int o = 32; o; o >>= 1) { s0 += __shfl_xor(s0, o); s1 += __shfl_xor(s1, o); }
            if (l == 0) {
                scal_part[y * 32 + b]      = s0;
                scal_part[y * 32 + 16 + b] = s1;
            }
        }
    }

    int j0 = x * JC + l * 4;

    // issue ALL 16 row loads up front (16 x 16B outstanding per lane)
    const float* wp = Wm + (size_t)(i0 + w * WR) * NN + j0;
    float4 buf[WR];
    #pragma unroll
    for (int r = 0; r < WR; ++r) buf[r] = *(const float4*)(wp + (size_t)r * NN);

    float4 acc[BB];
    #pragma unroll
    for (int b = 0; b < BB; ++b) acc[b] = make_float4(0.f, 0.f, 0.f, 0.f);

    // 4 rows per step; c_lds read is a float4 broadcast across rows
    #pragma unroll
    for (int rg = 0; rg < 4; ++rg) {
        float4 wv0 = buf[rg * 4 + 0], wv1 = buf[rg * 4 + 1];
        float4 wv2 = buf[rg * 4 + 2], wv3 = buf[rg * 4 + 3];
        int base = w * WR + rg * 4;
#define FMA16(b) { \
        float4 cr = *(const float4*)&c_lds[(b) * ROWS + base]; \
        acc[b].x += cr.x * wv0.x + cr.y * wv1.x + cr.z * wv2.x + cr.w * wv3.x; \
        acc[b].y += cr.x * wv0.y + cr.y * wv1.y + cr.z * wv2.y + cr.w * wv3.y; \
        acc[b].z += cr.x * wv0.z + cr.y * wv1.z + cr.z * wv2.z + cr.w * wv3.z; \
        acc[b].w += cr.x * wv0.w + cr.y * wv1.w + cr.z * wv2.w + cr.w * wv3.w; }
        FMA16(0)  FMA16(1)  FMA16(2)  FMA16(3)
        FMA16(4)  FMA16(5)  FMA16(6)  FMA16(7)
        FMA16(8)  FMA16(9)  FMA16(10) FMA16(11)
        FMA16(12) FMA16(13) FMA16(14) FMA16(15)
#undef FMA16
    }

    // tree-reduce 4 waves: [b][lane] float4, contiguous b128 ops
    if (w >= 2) {
        float4* rb = &red[(w - 2) * BB * 64];
        #pragma unroll
        for (int b = 0; b < BB; ++b) rb[b * 64 + l] = acc[b];
    }
    __syncthreads();
    if (w < 2) {
        const float4* rb = &red[w * BB * 64];
        #pragma unroll
        for (int b = 0; b < BB; ++b) {
            float4 v = rb[b * 64 + l];
            acc[b].x += v.x; acc[b].y += v.y; acc[b].z += v.z; acc[b].w += v.w;
        }
    }
    __syncthreads();
    if (w == 1) {
        #pragma unroll
        for (int b = 0; b < BB; ++b) red[b * 64 + l] = acc[b];
    }
    __syncthreads();
    if (w == 0) {
        float* pp = part + (size_t)y * BN + j0;
        #pragma unroll
        for (int b = 0; b < BB; ++b) {
            float4 v = red[b * 64 + l];
            acc[b].x += v.x; acc[b].y += v.y; acc[b].z += v.z; acc[b].w += v.w;
            *(float4*)(pp + (size_t)b * NN) = acc[b];
        }
    }
}

// ---------------- Kernel B: X + reduce partials + finalize ----------------
__global__ __launch_bounds__(256) void snn_post(
    const float* __restrict__ V, const float* __restrict__ th,
    const float* __restrict__ xpost,
    const float* __restrict__ part, const float* __restrict__ scal_part,
    float* __restrict__ out_X, float* __restrict__ out_V)
{
    int idx = blockIdx.x * 256 + threadIdx.x;
    int b = idx >> 11;                   // block-uniform
    float c1 = 0.f, c2 = 0.f, c3 = 0.f, c4 = 0.f;
    #pragma unroll
    for (int y = 0; y < YINT; ++y) {
        c1 += scal_part[y * 32 + b];
        c2 += scal_part[y * 32 + 16 + b];
    }
    #pragma unroll
    for (int y = YINT; y < YTOT; ++y) {
        c3 += scal_part[y * 32 + b];
        c4 += scal_part[y * 32 + 16 + b];
    }
    float v = V[idx];
    float x = 1.f / (1.f + expf(-(v - 1.f - th[idx]) * 5.f));
    out_X[idx] = x;
    float s = 0.f;
    #pragma unroll
    for (int y = 0; y < YTOT; ++y) s += part[(size_t)y * BN + idx];
    float c = s + 0.01f * (c1 + c3) * x - 0.012f * (c2 + c4) * xpost[idx];
    out_V[idx] = 0.9f * v * (1.f - x) + c;
}

extern "C" void kernel_launch(void* const* d_in, const int* in_sizes, int n_in,
                              void* d_out, int out_size, void* d_ws, size_t ws_size,
                              hipStream_t stream) {
    const float* FF       = (const float*)d_in[0];
    const float* V        = (const float*)d_in[1];
    const float* th       = (const float*)d_in[2];
    const float* Xbuf     = (const float*)d_in[3];
    const float* stp      = (const float*)d_in[4];
    const float* xpre_int = (const float*)d_in[5];
    const float* xpost    = (const float*)d_in[6];
    const float* xpre_ff  = (const float*)d_in[7];
    const float* Wint     = (const float*)d_in[8];
    const float* Wff      = (const float*)d_in[9];
    float* out = (float*)d_out;
    float* ws  = (float*)d_ws;

    float* part = ws;                    // 40 * 32768 floats (plain stores)
    float* sp   = ws + YTOT * BN;        // 1280 floats (plain stores)

    snn_gemv<<<dim3(NX, YTOT), 256, 0, stream>>>(
        Wint, Wff, Xbuf, stp, FF, xpre_int, xpre_ff, part, sp);

    snn_post<<<BN / 256, 256, 0, stream>>>(
        V, th, xpost, part, sp, out, out + BN);
}